// Round 3
// baseline (356.548 us; speedup 1.0000x reference)
//
#include <hip/hip_runtime.h>
#include <hip/hip_bf16.h>
#include <math.h>

#define BB 4
#define NT 1024
#define NSP 256
#define C 128
#define HEADS 8
#define HID 340
#define HID2 680
#define EPS 1e-5f

// workspace float offsets
#define WS_Q    0
#define WS_K    524288
#define WS_VT   1048576
#define WS_AO   1572864
#define WS_X1   2097152
#define WS_XN2  2621440
#define WS_PIN  3145728
#define WS_GLU  5931008
#define WS_MISC 7323648

typedef __bf16 bf16x8 __attribute__((ext_vector_type(8)));
typedef float f32x4 __attribute__((ext_vector_type(4)));

__device__ __forceinline__ float rfl(float v) {
    return __uint_as_float(__builtin_amdgcn_readfirstlane(__float_as_uint(v)));
}

// ---------------- K0: precompute piecewise-linear bias-MLP coefficients ----------------
__global__ void k0_prep(const float* __restrict__ bw1, const float* __restrict__ bb1,
                        const float* __restrict__ bw2, float* __restrict__ misc) {
    int t = threadIdx.x;
    if (t < HEADS) {
        float P = 0.f, Nn = 0.f;
        for (int k = 0; k < 16; ++k) {
            float w1 = bw1[k];
            float w2 = bw2[t * 16 + k];
            if (w1 > 0.f) P += w2 * w1; else Nn += w2 * w1;
        }
        misc[t] = P;
        misc[8 + t] = Nn;
    }
    if (t == 0) {
        int f = 1;
        for (int k = 0; k < 16; ++k) if (bb1[k] != 0.f) f = 0;
        misc[16] = (float)f;
    }
}

// ---------------- K1: LN1 + QKV projection (8 tokens / block) ----------------
__global__ __launch_bounds__(256) void k1_ln_qkv(
    const float* __restrict__ x, const float* __restrict__ s1, const float* __restrict__ b1,
    const float* __restrict__ qkv_w, const float* __restrict__ qkv_b, float* __restrict__ ws) {
    __shared__ float sxn[8][C];
    __shared__ float part[4][2];
    int tid = threadIdx.x;
    int g = tid >> 7, c = tid & 127;
    int wv = tid >> 6, lane = tid & 63;
    int tb = blockIdx.x * 8;

    for (int pass = 0; pass < 4; ++pass) {
        int tok = pass * 2 + g;
        float v = x[(size_t)(tb + tok) * C + c];
        float s = v, sq = v * v;
        #pragma unroll
        for (int off = 32; off; off >>= 1) { s += __shfl_xor(s, off); sq += __shfl_xor(sq, off); }
        if (lane == 0) { part[wv][0] = s; part[wv][1] = sq; }
        __syncthreads();
        float tot = part[g * 2][0] + part[g * 2 + 1][0];
        float tot2 = part[g * 2][1] + part[g * 2 + 1][1];
        float m = tot * (1.0f / C);
        float var = tot2 * (1.0f / C) - m * m;
        float inv = rsqrtf(var + EPS);
        sxn[tok][c] = (v - m) * inv * s1[c] + b1[c];
        __syncthreads();
    }

    float* qw = ws + WS_Q;
    float* kw = ws + WS_K;
    float* vtw = ws + WS_VT;
    for (int oo = tid; oo < 384; oo += 256) {
        const float4* wr = (const float4*)(qkv_w + (size_t)oo * C);
        float bbv = qkv_b[oo];
        float acc[8];
        #pragma unroll
        for (int t = 0; t < 8; ++t) acc[t] = bbv;
        #pragma unroll 4
        for (int ic4 = 0; ic4 < 32; ++ic4) {
            float4 w4 = wr[ic4];
            #pragma unroll
            for (int t = 0; t < 8; ++t) {
                acc[t] += w4.x * sxn[t][ic4 * 4 + 0] + w4.y * sxn[t][ic4 * 4 + 1]
                        + w4.z * sxn[t][ic4 * 4 + 2] + w4.w * sxn[t][ic4 * 4 + 3];
            }
        }
        int m3 = oo >> 7, h = (oo >> 4) & 7, dd = oo & 15;
        for (int t = 0; t < 8; ++t) {
            int tok = tb + t;
            int b = tok >> 10, i = tok & 1023;
            if (m3 == 0)      qw[(size_t)tok * C + h * 16 + dd] = acc[t] * 0.25f; // fold d^-0.5
            else if (m3 == 1) kw[(((size_t)b * 8 + h) * NT + i) * 16 + dd] = acc[t];
            else              vtw[(((size_t)b * 8 + h) * 16 + dd) * NT + i] = acc[t];
        }
    }
}

// ---------------- K2a: wave-independent logits + bias-MLP + softmax + attn write ----------------
// wave-task = (b, 4-row group, head). j = lane*16 + k. No LDS, no __syncthreads.
__global__ __launch_bounds__(512) void k2a_sm(
    const float* __restrict__ bias, const float* __restrict__ bb2v,
    const float* __restrict__ bw1v, const float* __restrict__ bb1v, const float* __restrict__ bw2v,
    const float* __restrict__ ws, float* __restrict__ attn_out) {
    int tid = threadIdx.x;
    int wv = tid >> 6, lane = tid & 63;
    int b = blockIdx.x >> 8;
    int i0 = (blockIdx.x & 255) << 2;
    int h = wv;
    const float* qw = ws + WS_Q;
    const float* kw = ws + WS_K;
    const float* misc = ws + WS_MISC;

    float Ph = misc[h], Nh = misc[8 + h], c2 = bb2v[h];
    bool fast = (misc[16] != 0.0f);

    // logits init = lie-bias term (consumes bias directly, no persistent bias regs)
    float lg[4][16];
    #pragma unroll
    for (int r = 0; r < 4; ++r) {
        const float4* bp = (const float4*)(bias + ((size_t)(b * NT + i0 + r)) * NT + lane * 16);
        #pragma unroll
        for (int q4 = 0; q4 < 4; ++q4) {
            float4 t4 = bp[q4];
            float bv[4] = {t4.x, t4.y, t4.z, t4.w};
            #pragma unroll
            for (int cc = 0; cc < 4; ++cc) {
                float bvv = bv[cc];
                float lb;
                if (fast) {
                    lb = bvv * (bvv > 0.f ? Ph : Nh) + c2;
                } else {
                    lb = c2;
                    for (int k = 0; k < 16; ++k) {
                        float t = bvv * bw1v[k] + bb1v[k];
                        if (t > 0.f) lb += bw2v[h * 16 + k] * t;
                    }
                }
                lg[r][q4 * 4 + cc] = lb;
            }
        }
    }

    // dot in two d-halves (q held in SGPRs via readfirstlane; 32 live at a time)
    #pragma unroll
    for (int half = 0; half < 2; ++half) {
        float qs[4][8];
        #pragma unroll
        for (int r = 0; r < 4; ++r) {
            const float* qb = qw + ((size_t)(b * NT + i0 + r)) * C + h * 16 + half * 8;
            float4 qa = *(const float4*)(qb);
            float4 qb4 = *(const float4*)(qb + 4);
            qs[r][0] = rfl(qa.x); qs[r][1] = rfl(qa.y); qs[r][2] = rfl(qa.z); qs[r][3] = rfl(qa.w);
            qs[r][4] = rfl(qb4.x); qs[r][5] = rfl(qb4.y); qs[r][6] = rfl(qb4.z); qs[r][7] = rfl(qb4.w);
        }
        const float* kb = kw + (size_t)(b * 8 + h) * NT * 16 + half * 8;
        #pragma unroll 4
        for (int k = 0; k < 16; ++k) {
            int j = lane * 16 + k;
            const float4* kr = (const float4*)(kb + (size_t)j * 16);
            float4 k0 = kr[0], k1 = kr[1];
            #pragma unroll
            for (int r = 0; r < 4; ++r) {
                lg[r][k] += qs[r][0] * k0.x + qs[r][1] * k0.y + qs[r][2] * k0.z + qs[r][3] * k0.w
                          + qs[r][4] * k1.x + qs[r][5] * k1.y + qs[r][6] * k1.z + qs[r][7] * k1.w;
            }
        }
    }

    // per-row softmax (wave-local) + store
    #pragma unroll
    for (int r = 0; r < 4; ++r) {
        float mx = lg[r][0];
        #pragma unroll
        for (int k = 1; k < 16; ++k) mx = fmaxf(mx, lg[r][k]);
        #pragma unroll
        for (int off = 32; off; off >>= 1) mx = fmaxf(mx, __shfl_xor(mx, off));
        float s = 0.f;
        #pragma unroll
        for (int k = 0; k < 16; ++k) { lg[r][k] = __expf(lg[r][k] - mx); s += lg[r][k]; }
        #pragma unroll
        for (int off = 32; off; off >>= 1) s += __shfl_xor(s, off);
        float inv = 1.0f / s;
        float* gbase = attn_out + ((size_t)(b * 8 + h) * NT + i0 + r) * NT + lane * 16;
        #pragma unroll
        for (int q4 = 0; q4 < 4; ++q4) {
            float4 o;
            o.x = lg[r][q4 * 4 + 0] * inv; o.y = lg[r][q4 * 4 + 1] * inv;
            o.z = lg[r][q4 * 4 + 2] * inv; o.w = lg[r][q4 * 4 + 3] * inv;
            *(float4*)(gbase + q4 * 4) = o;
        }
    }
}

// ---------------- K2b: PV via bf16 MFMA (A=attn rows, B=V^T staged in LDS) ----------------
__global__ __launch_bounds__(256) void k2b_pv(const float* __restrict__ attn,
                                              const float* __restrict__ ws_ro,
                                              float* __restrict__ ws_out) {
    __shared__ __bf16 sVT[16][1032];   // V^T bf16, padded row
    int tid = threadIdx.x;
    int blk = blockIdx.x;              // 512: bh = blk>>4, itile = blk&15
    int bh = blk >> 4;
    int i0 = (blk & 15) * 64;
    const float* vt = ws_ro + WS_VT + (size_t)bh * 16 * NT;

    #pragma unroll
    for (int s = 0; s < 16; ++s) {
        int f4 = tid + 256 * s;
        int dd = f4 >> 8, jq = f4 & 255;
        float4 v4 = *(const float4*)(vt + ((size_t)dd << 10) + jq * 4);
        sVT[dd][jq * 4 + 0] = (__bf16)v4.x;
        sVT[dd][jq * 4 + 1] = (__bf16)v4.y;
        sVT[dd][jq * 4 + 2] = (__bf16)v4.z;
        sVT[dd][jq * 4 + 3] = (__bf16)v4.w;
    }
    __syncthreads();

    int wv = tid >> 6, lane = tid & 63;
    int row = lane & 15, kg = lane >> 4;
    const float* pbase = attn + ((size_t)bh * NT + i0 + wv * 16 + row) * NT;
    f32x4 acc = {0.f, 0.f, 0.f, 0.f};
    #pragma unroll 4
    for (int kt = 0; kt < 32; ++kt) {
        int k0 = kt * 32 + kg * 8;
        float4 a0 = *(const float4*)(pbase + k0);
        float4 a1 = *(const float4*)(pbase + k0 + 4);
        bf16x8 af;
        af[0] = (__bf16)a0.x; af[1] = (__bf16)a0.y; af[2] = (__bf16)a0.z; af[3] = (__bf16)a0.w;
        af[4] = (__bf16)a1.x; af[5] = (__bf16)a1.y; af[6] = (__bf16)a1.z; af[7] = (__bf16)a1.w;
        bf16x8 bfv = *(const bf16x8*)&sVT[row][k0];
        acc = __builtin_amdgcn_mfma_f32_16x16x32_bf16(af, bfv, acc, 0, 0, 0);
    }
    int b = bh >> 3, h = bh & 7;
    float* ao = ws_out + WS_AO;
    #pragma unroll
    for (int q = 0; q < 4; ++q) {
        int irow = i0 + wv * 16 + kg * 4 + q;    // C/D: row=(lane>>4)*4+q, col=lane&15
        ao[((size_t)(b * NT + irow)) * C + h * 16 + row] = acc[q];
    }
}

// ---------------- K3: proj + residual1 + LN2 (8 tokens / block) ----------------
__global__ __launch_bounds__(256) void k3_proj(
    const float* __restrict__ x, const float* __restrict__ proj_w, const float* __restrict__ proj_b,
    const float* __restrict__ g1, const float* __restrict__ s2, const float* __restrict__ b2,
    float* __restrict__ ws) {
    __shared__ float sao[8 * C];
    __shared__ float part[8][4];
    int tid = threadIdx.x;
    int g = tid >> 7, c = tid & 127;
    int wvin = (tid >> 6) & 1, lane = tid & 63;
    int tb = blockIdx.x * 8;
    const float* ao = ws + WS_AO;
    ((float4*)sao)[tid] = ((const float4*)(ao + (size_t)tb * C))[tid];
    __syncthreads();

    float pb = proj_b[c];
    float acc[4] = {pb, pb, pb, pb};
    const float4* wr = (const float4*)(proj_w + (size_t)c * C);
    const float4* a0 = (const float4*)(sao + (g * 4 + 0) * C);
    const float4* a1 = (const float4*)(sao + (g * 4 + 1) * C);
    const float4* a2 = (const float4*)(sao + (g * 4 + 2) * C);
    const float4* a3 = (const float4*)(sao + (g * 4 + 3) * C);
    #pragma unroll 4
    for (int q = 0; q < 32; ++q) {
        float4 w4 = wr[q];
        float4 v0 = a0[q], v1 = a1[q], v2 = a2[q], v3 = a3[q];
        acc[0] += w4.x * v0.x + w4.y * v0.y + w4.z * v0.z + w4.w * v0.w;
        acc[1] += w4.x * v1.x + w4.y * v1.y + w4.z * v1.z + w4.w * v1.w;
        acc[2] += w4.x * v2.x + w4.y * v2.y + w4.z * v2.z + w4.w * v2.w;
        acc[3] += w4.x * v3.x + w4.y * v3.y + w4.z * v3.z + w4.w * v3.w;
    }
    float gv = g1[c], s2v = s2[c], b2v = b2[c];
    float x1v[4];
    #pragma unroll
    for (int t = 0; t < 4; ++t) {
        int tok = tb + g * 4 + t;
        float x1 = x[(size_t)tok * C + c] + gv * acc[t];
        x1v[t] = x1;
        ws[WS_X1 + (size_t)tok * C + c] = x1;
        float s = x1, sq = x1 * x1;
        #pragma unroll
        for (int off = 32; off; off >>= 1) { s += __shfl_xor(s, off); sq += __shfl_xor(sq, off); }
        if (lane == 0) { part[g * 4 + t][wvin * 2] = s; part[g * 4 + t][wvin * 2 + 1] = sq; }
    }
    __syncthreads();
    #pragma unroll
    for (int t = 0; t < 4; ++t) {
        int tok = tb + g * 4 + t;
        float tot = part[g * 4 + t][0] + part[g * 4 + t][2];
        float tot2 = part[g * 4 + t][1] + part[g * 4 + t][3];
        float m = tot * (1.0f / C);
        float var = tot2 * (1.0f / C) - m * m;
        float xn2 = (x1v[t] - m) * rsqrtf(var + EPS) * s2v + b2v;
        int bt = tok >> 8, n = tok & 255;
        ws[WS_XN2 + ((size_t)bt * C + c) * NSP + n] = xn2;
    }
}

// ---------------- K4: pin 1x1 conv (GEMM, 8 spatial / block) ----------------
__global__ __launch_bounds__(256) void k4_pin(const float* __restrict__ pin_w,
                                              const float* __restrict__ pin_b,
                                              float* __restrict__ ws) {
    __shared__ float sx[C][8];
    int tid = threadIdx.x;
    int bt = blockIdx.x >> 5;
    int n0 = (blockIdx.x & 31) << 3;
    const float* xn2 = ws + WS_XN2;
    float* po = ws + WS_PIN;
    for (int idx = tid; idx < 1024; idx += 256) {
        int ic = idx >> 3, nn = idx & 7;
        sx[ic][nn] = xn2[((size_t)bt * C + ic) * NSP + n0 + nn];
    }
    __syncthreads();
    for (int oc = tid; oc < HID2; oc += 256) {
        const float4* wr = (const float4*)(pin_w + (size_t)oc * C);
        float pb = pin_b[oc];
        float acc[8];
        #pragma unroll
        for (int nn = 0; nn < 8; ++nn) acc[nn] = pb;
        for (int ic4 = 0; ic4 < 32; ++ic4) {
            float4 w4 = wr[ic4];
            #pragma unroll
            for (int nn = 0; nn < 8; ++nn) {
                acc[nn] += w4.x * sx[ic4 * 4 + 0][nn] + w4.y * sx[ic4 * 4 + 1][nn]
                         + w4.z * sx[ic4 * 4 + 2][nn] + w4.w * sx[ic4 * 4 + 3][nn];
            }
        }
        float* ob = po + ((size_t)bt * HID2 + oc) * NSP + n0;
        #pragma unroll
        for (int nn = 0; nn < 8; ++nn) ob[nn] = acc[nn];
    }
}

// ---------------- K5: depthwise 3x3 + GLU (exact gelu) ----------------
__global__ __launch_bounds__(256) void k5_dwglu(const float* __restrict__ dw_w,
                                                const float* __restrict__ dw_b,
                                                float* __restrict__ ws) {
    __shared__ float sA[NSP], sG[NSP];
    int bt = blockIdx.x / HID;
    int c = blockIdx.x % HID;
    int px = threadIdx.x;
    int hh = px >> 4, wwp = px & 15;
    const float* po = ws + WS_PIN;
    sA[px] = po[((size_t)bt * HID2 + c) * NSP + px];
    sG[px] = po[((size_t)bt * HID2 + c + HID) * NSP + px];
    __syncthreads();
    float accA = dw_b[c], accG = dw_b[c + HID];
    #pragma unroll
    for (int kh = -1; kh <= 1; ++kh) {
        #pragma unroll
        for (int kw = -1; kw <= 1; ++kw) {
            int h2 = hh + kh, w2 = wwp + kw;
            bool ok = (h2 >= 0) & (h2 < 16) & (w2 >= 0) & (w2 < 16);
            float va = 0.f, vg = 0.f;
            if (ok) { int idx = h2 * 16 + w2; va = sA[idx]; vg = sG[idx]; }
            int kk = (kh + 1) * 3 + (kw + 1);
            accA += va * dw_w[(size_t)c * 9 + kk];
            accG += vg * dw_w[((size_t)c + HID) * 9 + kk];
        }
    }
    float gel = 0.5f * accA * (1.0f + erff(accA * 0.70710678118f));
    ws[WS_GLU + ((size_t)bt * HID + c) * NSP + px] = gel * accG;
}

// ---------------- K6: pout 1x1 conv + residual2 -> d_out x ----------------
__global__ __launch_bounds__(128) void k6_pout(const float* __restrict__ pout_w,
                                               const float* __restrict__ pout_b,
                                               const float* __restrict__ g2,
                                               float* __restrict__ ws, float* __restrict__ out) {
    __shared__ float sg[8][HID];
    int tid = threadIdx.x;
    int tb = blockIdx.x * 8;
    int bt = tb >> 8, n0 = tb & 255;
    const float* glu = ws + WS_GLU;
    for (int idx = tid; idx < 8 * HID; idx += 128) {
        int ic = idx >> 3, t = idx & 7;
        sg[t][ic] = glu[((size_t)bt * HID + ic) * NSP + n0 + t];
    }
    __syncthreads();
    int c = tid;
    const float4* wr4 = (const float4*)(pout_w + (size_t)c * HID);
    float acc[8];
    #pragma unroll
    for (int t = 0; t < 8; ++t) acc[t] = 0.f;
    for (int ic4 = 0; ic4 < 85; ++ic4) {
        float4 w4 = wr4[ic4];
        int ic = ic4 * 4;
        #pragma unroll
        for (int t = 0; t < 8; ++t) {
            acc[t] += w4.x * sg[t][ic] + w4.y * sg[t][ic + 1]
                    + w4.z * sg[t][ic + 2] + w4.w * sg[t][ic + 3];
        }
    }
    float pb = pout_b[c], gg = g2[c];
    const float* x1 = ws + WS_X1;
    for (int t = 0; t < 8; ++t) {
        size_t tok = tb + t;
        out[tok * C + c] = x1[tok * C + c] + gg * (acc[t] + pb);
    }
}

extern "C" void kernel_launch(void* const* d_in, const int* in_sizes, int n_in,
                              void* d_out, int out_size, void* d_ws, size_t ws_size,
                              hipStream_t stream) {
    const float* x      = (const float*)d_in[0];
    const float* bias   = (const float*)d_in[1];
    const float* ln1_s  = (const float*)d_in[2];
    const float* ln1_b  = (const float*)d_in[3];
    const float* qkv_w  = (const float*)d_in[4];
    const float* qkv_b  = (const float*)d_in[5];
    const float* proj_w = (const float*)d_in[6];
    const float* proj_b = (const float*)d_in[7];
    const float* bw1    = (const float*)d_in[8];
    const float* bb1    = (const float*)d_in[9];
    const float* bw2    = (const float*)d_in[10];
    const float* bb2    = (const float*)d_in[11];
    const float* ln2_s  = (const float*)d_in[12];
    const float* ln2_b  = (const float*)d_in[13];
    const float* pin_w  = (const float*)d_in[14];
    const float* pin_b  = (const float*)d_in[15];
    const float* dw_w   = (const float*)d_in[16];
    const float* dw_b   = (const float*)d_in[17];
    const float* pout_w = (const float*)d_in[18];
    const float* pout_b = (const float*)d_in[19];
    const float* gamma1 = (const float*)d_in[20];
    const float* gamma2 = (const float*)d_in[21];

    float* ws = (float*)d_ws;
    float* out = (float*)d_out;
    float* attn_out = out + (size_t)BB * NT * C;

    hipLaunchKernelGGL(k0_prep, dim3(1), dim3(64), 0, stream, bw1, bb1, bw2, ws + WS_MISC);
    hipLaunchKernelGGL(k1_ln_qkv, dim3(512), dim3(256), 0, stream, x, ln1_s, ln1_b, qkv_w, qkv_b, ws);
    hipLaunchKernelGGL(k2a_sm, dim3(1024), dim3(512), 0, stream, bias, bb2, bw1, bb1, bw2, ws, attn_out);
    hipLaunchKernelGGL(k2b_pv, dim3(512), dim3(256), 0, stream, attn_out, ws, ws);
    hipLaunchKernelGGL(k3_proj, dim3(512), dim3(256), 0, stream, x, proj_w, proj_b, gamma1, ln2_s, ln2_b, ws);
    hipLaunchKernelGGL(k4_pin, dim3(512), dim3(256), 0, stream, pin_w, pin_b, ws);
    hipLaunchKernelGGL(k5_dwglu, dim3(16 * HID), dim3(256), 0, stream, dw_w, dw_b, ws);
    hipLaunchKernelGGL(k6_pout, dim3(512), dim3(128), 0, stream, pout_w, pout_b, gamma2, ws, out);
}

// Round 4
// 250.144 us; speedup vs baseline: 1.4254x; 1.4254x over previous
//
#include <hip/hip_runtime.h>
#include <hip/hip_bf16.h>
#include <math.h>

#define BB 4
#define NT 1024
#define NSP 256
#define C 128
#define HEADS 8
#define HID 340
#define HID2 680
#define EPS 1e-5f

// workspace float offsets
#define WS_Q    0
#define WS_K    524288
#define WS_VT   1048576
#define WS_AO   1572864
#define WS_X1   2097152
#define WS_XN2  2621440
#define WS_PIN  3145728
#define WS_GLU  5931008
#define WS_MISC 7323648

typedef __bf16 bf16x8 __attribute__((ext_vector_type(8)));
typedef float f32x4 __attribute__((ext_vector_type(4)));

__device__ __forceinline__ float rfl(float v) {
    return __uint_as_float(__builtin_amdgcn_readfirstlane(__float_as_uint(v)));
}

// ---------------- K0: precompute piecewise-linear bias-MLP coefficients ----------------
__global__ void k0_prep(const float* __restrict__ bw1, const float* __restrict__ bb1,
                        const float* __restrict__ bw2, float* __restrict__ misc) {
    int t = threadIdx.x;
    if (t < HEADS) {
        float P = 0.f, Nn = 0.f;
        for (int k = 0; k < 16; ++k) {
            float w1 = bw1[k];
            float w2 = bw2[t * 16 + k];
            if (w1 > 0.f) P += w2 * w1; else Nn += w2 * w1;
        }
        misc[t] = P;
        misc[8 + t] = Nn;
    }
    if (t == 0) {
        int f = 1;
        for (int k = 0; k < 16; ++k) if (bb1[k] != 0.f) f = 0;
        misc[16] = (float)f;
    }
}

// ---------------- K1: LN1 + QKV projection (8 tokens / block) ----------------
__global__ __launch_bounds__(256) void k1_ln_qkv(
    const float* __restrict__ x, const float* __restrict__ s1, const float* __restrict__ b1,
    const float* __restrict__ qkv_w, const float* __restrict__ qkv_b, float* __restrict__ ws) {
    __shared__ float sxn[8][C];
    __shared__ float part[4][2];
    int tid = threadIdx.x;
    int g = tid >> 7, c = tid & 127;
    int wv = tid >> 6, lane = tid & 63;
    int tb = blockIdx.x * 8;

    for (int pass = 0; pass < 4; ++pass) {
        int tok = pass * 2 + g;
        float v = x[(size_t)(tb + tok) * C + c];
        float s = v, sq = v * v;
        #pragma unroll
        for (int off = 32; off; off >>= 1) { s += __shfl_xor(s, off); sq += __shfl_xor(sq, off); }
        if (lane == 0) { part[wv][0] = s; part[wv][1] = sq; }
        __syncthreads();
        float tot = part[g * 2][0] + part[g * 2 + 1][0];
        float tot2 = part[g * 2][1] + part[g * 2 + 1][1];
        float m = tot * (1.0f / C);
        float var = tot2 * (1.0f / C) - m * m;
        float inv = rsqrtf(var + EPS);
        sxn[tok][c] = (v - m) * inv * s1[c] + b1[c];
        __syncthreads();
    }

    float* qw = ws + WS_Q;
    float* kw = ws + WS_K;
    float* vtw = ws + WS_VT;
    for (int oo = tid; oo < 384; oo += 256) {
        const float4* wr = (const float4*)(qkv_w + (size_t)oo * C);
        float bbv = qkv_b[oo];
        float acc[8];
        #pragma unroll
        for (int t = 0; t < 8; ++t) acc[t] = bbv;
        #pragma unroll 4
        for (int ic4 = 0; ic4 < 32; ++ic4) {
            float4 w4 = wr[ic4];
            #pragma unroll
            for (int t = 0; t < 8; ++t) {
                acc[t] += w4.x * sxn[t][ic4 * 4 + 0] + w4.y * sxn[t][ic4 * 4 + 1]
                        + w4.z * sxn[t][ic4 * 4 + 2] + w4.w * sxn[t][ic4 * 4 + 3];
            }
        }
        int m3 = oo >> 7, h = (oo >> 4) & 7, dd = oo & 15;
        for (int t = 0; t < 8; ++t) {
            int tok = tb + t;
            int b = tok >> 10, i = tok & 1023;
            if (m3 == 0)      qw[(size_t)tok * C + h * 16 + dd] = acc[t] * 0.25f; // fold d^-0.5
            else if (m3 == 1) kw[(((size_t)b * 8 + h) * NT + i) * 16 + dd] = acc[t];
            else              vtw[(((size_t)b * 8 + h) * 16 + dd) * NT + i] = acc[t];
        }
    }
}

// ---------------- K2a: wave-independent logits + bias-MLP + softmax + attn write ----------------
// wave-task = (b, 4-row group, head). lane owns j = k*256 + lane*4 + c (k,c in 0..3):
// bias loads & attn stores are coalesced float4; K loads are 256B/lane contiguous (L2-hot).
__global__ __launch_bounds__(512) void k2a_sm(
    const float* __restrict__ bias, const float* __restrict__ bb2v,
    const float* __restrict__ bw1v, const float* __restrict__ bb1v, const float* __restrict__ bw2v,
    const float* __restrict__ ws, float* __restrict__ attn_out) {
    int tid = threadIdx.x;
    int wv = tid >> 6, lane = tid & 63;
    int b = blockIdx.x >> 8;
    int i0 = (blockIdx.x & 255) << 2;
    int h = wv;
    const float* qw = ws + WS_Q;
    const float* kw = ws + WS_K;
    const float* misc = ws + WS_MISC;

    float Ph = misc[h], Nh = misc[8 + h], c2 = bb2v[h];
    bool fast = (misc[16] != 0.0f);

    // logits init = lie-bias term; lg[r][k*4+c] corresponds to j = k*256 + lane*4 + c
    float lg[4][16];
    #pragma unroll
    for (int r = 0; r < 4; ++r) {
        const float4* bp = (const float4*)(bias + ((size_t)(b * NT + i0 + r)) * NT);
        #pragma unroll
        for (int k = 0; k < 4; ++k) {
            float4 t4 = bp[k * 64 + lane];
            float bv[4] = {t4.x, t4.y, t4.z, t4.w};
            #pragma unroll
            for (int cc = 0; cc < 4; ++cc) {
                float bvv = bv[cc];
                float lb;
                if (fast) {
                    lb = bvv * (bvv > 0.f ? Ph : Nh) + c2;
                } else {
                    lb = c2;
                    for (int kk = 0; kk < 16; ++kk) {
                        float t = bvv * bw1v[kk] + bb1v[kk];
                        if (t > 0.f) lb += bw2v[h * 16 + kk] * t;
                    }
                }
                lg[r][k * 4 + cc] = lb;
            }
        }
    }

    // dot in two d-halves (q held in SGPRs via readfirstlane; 32 live at a time)
    #pragma unroll
    for (int half = 0; half < 2; ++half) {
        float qs[4][8];
        #pragma unroll
        for (int r = 0; r < 4; ++r) {
            const float* qb = qw + ((size_t)(b * NT + i0 + r)) * C + h * 16 + half * 8;
            float4 qa = *(const float4*)(qb);
            float4 qb4 = *(const float4*)(qb + 4);
            qs[r][0] = rfl(qa.x); qs[r][1] = rfl(qa.y); qs[r][2] = rfl(qa.z); qs[r][3] = rfl(qa.w);
            qs[r][4] = rfl(qb4.x); qs[r][5] = rfl(qb4.y); qs[r][6] = rfl(qb4.z); qs[r][7] = rfl(qb4.w);
        }
        const float* kb = kw + (size_t)(b * 8 + h) * NT * 16 + half * 8;
        #pragma unroll
        for (int k = 0; k < 4; ++k) {
            // lane reads K rows j = k*256 + lane*4 + c, c=0..3 (256B contiguous per lane)
            const float* krow = kb + (size_t)(k * 256 + lane * 4) * 16;
            #pragma unroll
            for (int cc = 0; cc < 4; ++cc) {
                float4 k0 = *(const float4*)(krow + cc * 16);
                float4 k1 = *(const float4*)(krow + cc * 16 + 4);
                #pragma unroll
                for (int r = 0; r < 4; ++r) {
                    lg[r][k * 4 + cc] += qs[r][0] * k0.x + qs[r][1] * k0.y + qs[r][2] * k0.z + qs[r][3] * k0.w
                                       + qs[r][4] * k1.x + qs[r][5] * k1.y + qs[r][6] * k1.z + qs[r][7] * k1.w;
                }
            }
        }
    }

    // per-row softmax (wave-local) + coalesced store
    #pragma unroll
    for (int r = 0; r < 4; ++r) {
        float mx = lg[r][0];
        #pragma unroll
        for (int k = 1; k < 16; ++k) mx = fmaxf(mx, lg[r][k]);
        #pragma unroll
        for (int off = 32; off; off >>= 1) mx = fmaxf(mx, __shfl_xor(mx, off));
        float s = 0.f;
        #pragma unroll
        for (int k = 0; k < 16; ++k) { lg[r][k] = __expf(lg[r][k] - mx); s += lg[r][k]; }
        #pragma unroll
        for (int off = 32; off; off >>= 1) s += __shfl_xor(s, off);
        float inv = 1.0f / s;
        float* gbase = attn_out + ((size_t)(b * 8 + h) * NT + i0 + r) * NT;
        #pragma unroll
        for (int k = 0; k < 4; ++k) {
            float4 o;
            o.x = lg[r][k * 4 + 0] * inv; o.y = lg[r][k * 4 + 1] * inv;
            o.z = lg[r][k * 4 + 2] * inv; o.w = lg[r][k * 4 + 3] * inv;
            *(float4*)(gbase + k * 256 + lane * 4) = o;
        }
    }
}

// ---------------- K2b: PV via bf16 MFMA (A=attn rows, B=V^T staged in LDS) ----------------
__global__ __launch_bounds__(256) void k2b_pv(const float* __restrict__ attn,
                                              const float* __restrict__ ws_ro,
                                              float* __restrict__ ws_out) {
    __shared__ __bf16 sVT[16][1032];   // V^T bf16, padded row
    int tid = threadIdx.x;
    int blk = blockIdx.x;              // 512: bh = blk>>4, itile = blk&15
    int bh = blk >> 4;
    int i0 = (blk & 15) * 64;
    const float* vt = ws_ro + WS_VT + (size_t)bh * 16 * NT;

    #pragma unroll
    for (int s = 0; s < 16; ++s) {
        int f4 = tid + 256 * s;
        int dd = f4 >> 8, jq = f4 & 255;
        float4 v4 = *(const float4*)(vt + ((size_t)dd << 10) + jq * 4);
        sVT[dd][jq * 4 + 0] = (__bf16)v4.x;
        sVT[dd][jq * 4 + 1] = (__bf16)v4.y;
        sVT[dd][jq * 4 + 2] = (__bf16)v4.z;
        sVT[dd][jq * 4 + 3] = (__bf16)v4.w;
    }
    __syncthreads();

    int wv = tid >> 6, lane = tid & 63;
    int row = lane & 15, kg = lane >> 4;
    const float* pbase = attn + ((size_t)bh * NT + i0 + wv * 16 + row) * NT;
    f32x4 acc = {0.f, 0.f, 0.f, 0.f};
    #pragma unroll 4
    for (int kt = 0; kt < 32; ++kt) {
        int k0 = kt * 32 + kg * 8;
        float4 a0 = *(const float4*)(pbase + k0);
        float4 a1 = *(const float4*)(pbase + k0 + 4);
        bf16x8 af;
        af[0] = (__bf16)a0.x; af[1] = (__bf16)a0.y; af[2] = (__bf16)a0.z; af[3] = (__bf16)a0.w;
        af[4] = (__bf16)a1.x; af[5] = (__bf16)a1.y; af[6] = (__bf16)a1.z; af[7] = (__bf16)a1.w;
        bf16x8 bfv = *(const bf16x8*)&sVT[row][k0];
        acc = __builtin_amdgcn_mfma_f32_16x16x32_bf16(af, bfv, acc, 0, 0, 0);
    }
    int b = bh >> 3, h = bh & 7;
    float* ao = ws_out + WS_AO;
    #pragma unroll
    for (int q = 0; q < 4; ++q) {
        int irow = i0 + wv * 16 + kg * 4 + q;    // C/D: row=(lane>>4)*4+q, col=lane&15
        ao[((size_t)(b * NT + irow)) * C + h * 16 + row] = acc[q];
    }
}

// ---------------- K3: proj + residual1 + LN2 (8 tokens / block) ----------------
__global__ __launch_bounds__(256) void k3_proj(
    const float* __restrict__ x, const float* __restrict__ proj_w, const float* __restrict__ proj_b,
    const float* __restrict__ g1, const float* __restrict__ s2, const float* __restrict__ b2,
    float* __restrict__ ws) {
    __shared__ float sao[8 * C];
    __shared__ float part[8][4];
    int tid = threadIdx.x;
    int g = tid >> 7, c = tid & 127;
    int wvin = (tid >> 6) & 1, lane = tid & 63;
    int tb = blockIdx.x * 8;
    const float* ao = ws + WS_AO;
    ((float4*)sao)[tid] = ((const float4*)(ao + (size_t)tb * C))[tid];
    __syncthreads();

    float pb = proj_b[c];
    float acc[4] = {pb, pb, pb, pb};
    const float4* wr = (const float4*)(proj_w + (size_t)c * C);
    const float4* a0 = (const float4*)(sao + (g * 4 + 0) * C);
    const float4* a1 = (const float4*)(sao + (g * 4 + 1) * C);
    const float4* a2 = (const float4*)(sao + (g * 4 + 2) * C);
    const float4* a3 = (const float4*)(sao + (g * 4 + 3) * C);
    #pragma unroll 4
    for (int q = 0; q < 32; ++q) {
        float4 w4 = wr[q];
        float4 v0 = a0[q], v1 = a1[q], v2 = a2[q], v3 = a3[q];
        acc[0] += w4.x * v0.x + w4.y * v0.y + w4.z * v0.z + w4.w * v0.w;
        acc[1] += w4.x * v1.x + w4.y * v1.y + w4.z * v1.z + w4.w * v1.w;
        acc[2] += w4.x * v2.x + w4.y * v2.y + w4.z * v2.z + w4.w * v2.w;
        acc[3] += w4.x * v3.x + w4.y * v3.y + w4.z * v3.z + w4.w * v3.w;
    }
    float gv = g1[c], s2v = s2[c], b2v = b2[c];
    float x1v[4];
    #pragma unroll
    for (int t = 0; t < 4; ++t) {
        int tok = tb + g * 4 + t;
        float x1 = x[(size_t)tok * C + c] + gv * acc[t];
        x1v[t] = x1;
        ws[WS_X1 + (size_t)tok * C + c] = x1;
        float s = x1, sq = x1 * x1;
        #pragma unroll
        for (int off = 32; off; off >>= 1) { s += __shfl_xor(s, off); sq += __shfl_xor(sq, off); }
        if (lane == 0) { part[g * 4 + t][wvin * 2] = s; part[g * 4 + t][wvin * 2 + 1] = sq; }
    }
    __syncthreads();
    #pragma unroll
    for (int t = 0; t < 4; ++t) {
        int tok = tb + g * 4 + t;
        float tot = part[g * 4 + t][0] + part[g * 4 + t][2];
        float tot2 = part[g * 4 + t][1] + part[g * 4 + t][3];
        float m = tot * (1.0f / C);
        float var = tot2 * (1.0f / C) - m * m;
        float xn2 = (x1v[t] - m) * rsqrtf(var + EPS) * s2v + b2v;
        int bt = tok >> 8, n = tok & 255;
        ws[WS_XN2 + ((size_t)bt * C + c) * NSP + n] = xn2;
    }
}

// ---------------- K4: pin 1x1 conv (GEMM, 8 spatial / block) ----------------
__global__ __launch_bounds__(256) void k4_pin(const float* __restrict__ pin_w,
                                              const float* __restrict__ pin_b,
                                              float* __restrict__ ws) {
    __shared__ float sx[C][8];
    int tid = threadIdx.x;
    int bt = blockIdx.x >> 5;
    int n0 = (blockIdx.x & 31) << 3;
    const float* xn2 = ws + WS_XN2;
    float* po = ws + WS_PIN;
    for (int idx = tid; idx < 1024; idx += 256) {
        int ic = idx >> 3, nn = idx & 7;
        sx[ic][nn] = xn2[((size_t)bt * C + ic) * NSP + n0 + nn];
    }
    __syncthreads();
    for (int oc = tid; oc < HID2; oc += 256) {
        const float4* wr = (const float4*)(pin_w + (size_t)oc * C);
        float pb = pin_b[oc];
        float acc[8];
        #pragma unroll
        for (int nn = 0; nn < 8; ++nn) acc[nn] = pb;
        for (int ic4 = 0; ic4 < 32; ++ic4) {
            float4 w4 = wr[ic4];
            #pragma unroll
            for (int nn = 0; nn < 8; ++nn) {
                acc[nn] += w4.x * sx[ic4 * 4 + 0][nn] + w4.y * sx[ic4 * 4 + 1][nn]
                         + w4.z * sx[ic4 * 4 + 2][nn] + w4.w * sx[ic4 * 4 + 3][nn];
            }
        }
        float* ob = po + ((size_t)bt * HID2 + oc) * NSP + n0;
        #pragma unroll
        for (int nn = 0; nn < 8; ++nn) ob[nn] = acc[nn];
    }
}

// ---------------- K5: depthwise 3x3 + GLU (exact gelu) ----------------
__global__ __launch_bounds__(256) void k5_dwglu(const float* __restrict__ dw_w,
                                                const float* __restrict__ dw_b,
                                                float* __restrict__ ws) {
    __shared__ float sA[NSP], sG[NSP];
    int bt = blockIdx.x / HID;
    int c = blockIdx.x % HID;
    int px = threadIdx.x;
    int hh = px >> 4, wwp = px & 15;
    const float* po = ws + WS_PIN;
    sA[px] = po[((size_t)bt * HID2 + c) * NSP + px];
    sG[px] = po[((size_t)bt * HID2 + c + HID) * NSP + px];
    __syncthreads();
    float accA = dw_b[c], accG = dw_b[c + HID];
    #pragma unroll
    for (int kh = -1; kh <= 1; ++kh) {
        #pragma unroll
        for (int kw = -1; kw <= 1; ++kw) {
            int h2 = hh + kh, w2 = wwp + kw;
            bool ok = (h2 >= 0) & (h2 < 16) & (w2 >= 0) & (w2 < 16);
            float va = 0.f, vg = 0.f;
            if (ok) { int idx = h2 * 16 + w2; va = sA[idx]; vg = sG[idx]; }
            int kk = (kh + 1) * 3 + (kw + 1);
            accA += va * dw_w[(size_t)c * 9 + kk];
            accG += vg * dw_w[((size_t)c + HID) * 9 + kk];
        }
    }
    float gel = 0.5f * accA * (1.0f + erff(accA * 0.70710678118f));
    ws[WS_GLU + ((size_t)bt * HID + c) * NSP + px] = gel * accG;
}

// ---------------- K6: pout 1x1 conv + residual2 -> d_out x ----------------
__global__ __launch_bounds__(128) void k6_pout(const float* __restrict__ pout_w,
                                               const float* __restrict__ pout_b,
                                               const float* __restrict__ g2,
                                               float* __restrict__ ws, float* __restrict__ out) {
    __shared__ float sg[8][HID];
    int tid = threadIdx.x;
    int tb = blockIdx.x * 8;
    int bt = tb >> 8, n0 = tb & 255;
    const float* glu = ws + WS_GLU;
    for (int idx = tid; idx < 8 * HID; idx += 128) {
        int ic = idx >> 3, t = idx & 7;
        sg[t][ic] = glu[((size_t)bt * HID + ic) * NSP + n0 + t];
    }
    __syncthreads();
    int c = tid;
    const float4* wr4 = (const float4*)(pout_w + (size_t)c * HID);
    float acc[8];
    #pragma unroll
    for (int t = 0; t < 8; ++t) acc[t] = 0.f;
    for (int ic4 = 0; ic4 < 85; ++ic4) {
        float4 w4 = wr4[ic4];
        int ic = ic4 * 4;
        #pragma unroll
        for (int t = 0; t < 8; ++t) {
            acc[t] += w4.x * sg[t][ic] + w4.y * sg[t][ic + 1]
                    + w4.z * sg[t][ic + 2] + w4.w * sg[t][ic + 3];
        }
    }
    float pb = pout_b[c], gg = g2[c];
    const float* x1 = ws + WS_X1;
    for (int t = 0; t < 8; ++t) {
        size_t tok = tb + t;
        out[tok * C + c] = x1[tok * C + c] + gg * (acc[t] + pb);
    }
}

extern "C" void kernel_launch(void* const* d_in, const int* in_sizes, int n_in,
                              void* d_out, int out_size, void* d_ws, size_t ws_size,
                              hipStream_t stream) {
    const float* x      = (const float*)d_in[0];
    const float* bias   = (const float*)d_in[1];
    const float* ln1_s  = (const float*)d_in[2];
    const float* ln1_b  = (const float*)d_in[3];
    const float* qkv_w  = (const float*)d_in[4];
    const float* qkv_b  = (const float*)d_in[5];
    const float* proj_w = (const float*)d_in[6];
    const float* proj_b = (const float*)d_in[7];
    const float* bw1    = (const float*)d_in[8];
    const float* bb1    = (const float*)d_in[9];
    const float* bw2    = (const float*)d_in[10];
    const float* bb2    = (const float*)d_in[11];
    const float* ln2_s  = (const float*)d_in[12];
    const float* ln2_b  = (const float*)d_in[13];
    const float* pin_w  = (const float*)d_in[14];
    const float* pin_b  = (const float*)d_in[15];
    const float* dw_w   = (const float*)d_in[16];
    const float* dw_b   = (const float*)d_in[17];
    const float* pout_w = (const float*)d_in[18];
    const float* pout_b = (const float*)d_in[19];
    const float* gamma1 = (const float*)d_in[20];
    const float* gamma2 = (const float*)d_in[21];

    float* ws = (float*)d_ws;
    float* out = (float*)d_out;
    float* attn_out = out + (size_t)BB * NT * C;

    hipLaunchKernelGGL(k0_prep, dim3(1), dim3(64), 0, stream, bw1, bb1, bw2, ws + WS_MISC);
    hipLaunchKernelGGL(k1_ln_qkv, dim3(512), dim3(256), 0, stream, x, ln1_s, ln1_b, qkv_w, qkv_b, ws);
    hipLaunchKernelGGL(k2a_sm, dim3(1024), dim3(512), 0, stream, bias, bb2, bw1, bb1, bw2, ws, attn_out);
    hipLaunchKernelGGL(k2b_pv, dim3(512), dim3(256), 0, stream, attn_out, ws, ws);
    hipLaunchKernelGGL(k3_proj, dim3(512), dim3(256), 0, stream, x, proj_w, proj_b, gamma1, ln2_s, ln2_b, ws);
    hipLaunchKernelGGL(k4_pin, dim3(512), dim3(256), 0, stream, pin_w, pin_b, ws);
    hipLaunchKernelGGL(k5_dwglu, dim3(16 * HID), dim3(256), 0, stream, dw_w, dw_b, ws);
    hipLaunchKernelGGL(k6_pout, dim3(512), dim3(128), 0, stream, pout_w, pout_b, gamma2, ws, out);
}